// Round 7
// baseline (2895.759 us; speedup 1.0000x reference)
//
#include <hip/hip_runtime.h>

#define NN 1024
#define NOPEN 128
#define NHID 256
#define NSTART 40
#define NCLOSE 3
#define NLAYERS 40
#define KSZ 9

static constexpr float H2 = 0.01f;     // h*h, h = 0.1
static constexpr float IN_EPS = 1e-5f; // instance norm eps

using floatx4 = __attribute__((ext_vector_type(4))) float;
using bfrag = __attribute__((ext_vector_type(8))) short; // 8 bf16 = 4 VGPRs

__device__ __forceinline__ ushort f2bf(float f) {
    union { float f; unsigned u; } v; v.f = f;
    unsigned r = v.u + 0x7fffu + ((v.u >> 16) & 1u); // RNE
    return (ushort)(r >> 16);
}

// weight transpose prep: lb<72 -> Wt[z][t][co][ci]; else WtT[z][t][ci][co]
__device__ __forceinline__ void prepw_piece(const float* __restrict__ W, ushort* __restrict__ Wt,
                                            ushort* __restrict__ WtT, int lb, int lsrc, int tid) {
    if (lb < 72) {
        int q = lb; int coq = q & 3; q >>= 2; int t = q % 9, z = q / 9;
        const float* Wz = W + (size_t)(lsrc * 2 + z) * (NHID * NOPEN * KSZ);
        ushort* Wo = Wt + ((size_t)z * 9 + t) * (NHID * NOPEN);
#pragma unroll
        for (int r = 0; r < 32; ++r) {
            int idx = r * 256 + tid;
            int co = coq * 64 + (idx >> 7), ci = idx & 127;
            Wo[co * NOPEN + ci] = f2bf(Wz[co * (NOPEN * KSZ) + ci * KSZ + t]);
        }
    } else {
        int q = lb - 72; int ciq = q & 3; q >>= 2; int t = q % 9, z = q / 9;
        const float* Wz = W + (size_t)(lsrc * 2 + z) * (NHID * NOPEN * KSZ);
        ushort* Wo = WtT + ((size_t)z * 9 + t) * (NOPEN * NHID);
#pragma unroll
        for (int r = 0; r < 32; ++r) {
            int idx = r * 256 + tid;
            int ci = ciq * 32 + (idx >> 8), co = idx & 255;
            Wo[ci * NHID + co] = f2bf(Wz[co * (NOPEN * KSZ) + ci * KSZ + t]);
        }
    }
}

// ---------------- opening: B0 = (Kopen@Z)^T [n][ci]; prepw(0); pads; Tacc=0; sig=0 ----------------
__global__ __launch_bounds__(256) void k_open(const float* __restrict__ Kopen, const float* __restrict__ Z,
                       float* __restrict__ B0, ushort* __restrict__ At0, ushort* __restrict__ At1,
                       const float* __restrict__ W, ushort* __restrict__ Wt,
                       ushort* __restrict__ WtT, float* __restrict__ Tacc, float* __restrict__ sig) {
    const int v = blockIdx.x, tid = threadIdx.x;
    if (v < 512) {
        int o = v >> 2, n = (v & 3) * 256 + tid;
        float acc = 0.f;
#pragma unroll
        for (int s = 0; s < NSTART; ++s)
            acc = fmaf(Kopen[o * NSTART + s], Z[s * NN + n], acc);
        B0[n * 128 + o] = acc;
    } else if (v < 656) {
        prepw_piece(W, Wt, WtT, v - 512, 0, tid);
    } else if (v == 656) {
        if (tid == 0) sig[0] = 0.f;
        for (int idx = tid; idx < 2048; idx += 256) {
            int a = idx >> 10, rr = idx & 1023;
            ushort* A = a ? At1 : At0;
            A[rr] = 0; A[1028 * 256 + rr] = 0;
        }
    } else {
        int w = v - 657;                      // 128 blocks zero Tacc
        *(float4*)&Tacc[(w * 256 + tid) * 4] = float4{0.f, 0.f, 0.f, 0.f};
    }
}

// ---------------- D2 from Zcur [n][ci]; sq in-block; sum(D2) -> sig ----------------
__global__ __launch_bounds__(256) void k_d2(const float* __restrict__ Zcur,
                                            float* __restrict__ D2, float* __restrict__ sig) {
    __shared__ __align__(16) float Zi[32 * 36];
    __shared__ __align__(16) float Zj[32 * 68];
    __shared__ float sqi[32], sqj[64];
    __shared__ float red[4];
    const int tid = threadIdx.x;
    const int tx = tid & 15, ty = tid >> 4;
    const int j0 = blockIdx.x * 64, i0 = blockIdx.y * 32;
    if (tid < 32) sqi[tid] = 0.f;
    else if (tid < 96) sqj[tid - 32] = 0.f;
    float acc[2][4] = {};
    for (int c0 = 0; c0 < NOPEN; c0 += 32) {
        for (int idx = tid; idx < 32 * 32; idx += 256) {
            int c = idx & 31, ii = idx >> 5;
            Zi[c * 36 + ii] = Zcur[(i0 + ii) * 128 + c0 + c];
        }
        for (int idx = tid; idx < 32 * 64; idx += 256) {
            int c = idx & 31, jj = idx >> 5;
            Zj[c * 68 + jj] = Zcur[(j0 + jj) * 128 + c0 + c];
        }
        __syncthreads();
        if (tid < 32) {
            float s = 0.f;
            for (int c = 0; c < 32; ++c) { float x = Zi[c * 36 + tid]; s = fmaf(x, x, s); }
            sqi[tid] += s;
        } else if (tid < 96) {
            int jj = tid - 32;
            float s = 0.f;
            for (int c = 0; c < 32; ++c) { float x = Zj[c * 68 + jj]; s = fmaf(x, x, s); }
            sqj[jj] += s;
        }
#pragma unroll 8
        for (int c = 0; c < 32; ++c) {
            float2 zi = *(const float2*)&Zi[c * 36 + ty * 2];
            float4 zj = *(const float4*)&Zj[c * 68 + tx * 4];
            acc[0][0] = fmaf(zi.x, zj.x, acc[0][0]);
            acc[0][1] = fmaf(zi.x, zj.y, acc[0][1]);
            acc[0][2] = fmaf(zi.x, zj.z, acc[0][2]);
            acc[0][3] = fmaf(zi.x, zj.w, acc[0][3]);
            acc[1][0] = fmaf(zi.y, zj.x, acc[1][0]);
            acc[1][1] = fmaf(zi.y, zj.y, acc[1][1]);
            acc[1][2] = fmaf(zi.y, zj.z, acc[1][2]);
            acc[1][3] = fmaf(zi.y, zj.w, acc[1][3]);
        }
        __syncthreads();
    }
    float part = 0.f;
#pragma unroll
    for (int m = 0; m < 2; ++m) {
        int i = i0 + ty * 2 + m;
        float sqi_v = sqi[ty * 2 + m];
        float4 d;
        d.x = fmaxf(sqi_v + sqj[tx * 4 + 0] - 2.f * acc[m][0], 0.f);
        d.y = fmaxf(sqi_v + sqj[tx * 4 + 1] - 2.f * acc[m][1], 0.f);
        d.z = fmaxf(sqi_v + sqj[tx * 4 + 2] - 2.f * acc[m][2], 0.f);
        d.w = fmaxf(sqi_v + sqj[tx * 4 + 3] - 2.f * acc[m][3], 0.f);
        *(float4*)&D2[(size_t)i * NN + j0 + tx * 4] = d;
        part += (d.x + d.y) + (d.z + d.w);
    }
#pragma unroll
    for (int off = 32; off > 0; off >>= 1) part += __shfl_down(part, off);
    if ((tid & 63) == 0) red[tid >> 6] = part;
    __syncthreads();
    if (tid == 0) atomicAdd(sig, red[0] + red[1] + red[2] + red[3]);
}

// ---------------- deg / L (unchanged) ----------------
__global__ void k_deg(const float* __restrict__ D2, const float* __restrict__ sig,
                      float* __restrict__ Dh) {
    __shared__ float red[4];
    int i = blockIdx.x, tid = threadIdx.x;
    float inv = 1.f / (sig[0] * (1.f / 1048576.f) + 1e-12f);
    float4 v = *(const float4*)&D2[(size_t)i * NN + tid * 4];
    float s = __expf(-v.x * inv) + __expf(-v.y * inv) + __expf(-v.z * inv) + __expf(-v.w * inv);
#pragma unroll
    for (int off = 32; off > 0; off >>= 1) s += __shfl_down(s, off);
    if ((tid & 63) == 0) red[tid >> 6] = s;
    __syncthreads();
    if (tid == 0) Dh[i] = rsqrtf(red[0] + red[1] + red[2] + red[3]);
}

__global__ void k_L(const float* __restrict__ D2, const float* __restrict__ sig,
                    const float* __restrict__ Dh, ushort* __restrict__ Lb) {
    int i = blockIdx.x, tid = threadIdx.x;
    int j = tid * 4;
    float inv = 1.f / (sig[0] * (1.f / 1048576.f) + 1e-12f);
    float dhi = Dh[i];
    float4 v = *(const float4*)&D2[(size_t)i * NN + j];
    float4 dj = *(const float4*)&Dh[j];
    float4 o;
    o.x = -dhi * dj.x * __expf(-v.x * inv);
    o.y = -dhi * dj.y * __expf(-v.y * inv);
    o.z = -dhi * dj.z * __expf(-v.z * inv);
    o.w = -dhi * dj.w * __expf(-v.w * inv);
    if (i == j + 0) o.x += 1.f;
    if (i == j + 1) o.y += 1.f;
    if (i == j + 2) o.z += 1.f;
    if (i == j + 3) o.w += 1.f;
    ushort4 ob; ob.x = f2bf(o.x); ob.y = f2bf(o.y); ob.z = f2bf(o.z); ob.w = f2bf(o.w);
    *(ushort4*)&Lb[(size_t)i * NN + j] = ob;
}

// ---------------- conv + fused leap: Znew = 2Zc - Zo - H2*Ta (staged bf16 + bias), MFMA conv ----------------
// grid (16 p, 8 co, 2 z). State layout [n][ci]. Blocks (y==0,z==0) also write Znew fp32.
__global__ __launch_bounds__(256) void k_conv2(const float* __restrict__ Zc, const float* __restrict__ Zo,
        const float* __restrict__ Ta, float* __restrict__ Zn, const float* __restrict__ BiasL,
        const ushort* __restrict__ Wt, float* __restrict__ C0, ushort* __restrict__ C1b) {
    const int z = blockIdx.z;
    const int p0 = blockIdx.x * 64, co0 = blockIdx.y * 32;
    __shared__ ushort Xs[72 * 136];
    __shared__ ushort Wl[9 * 32 * 136];
    const int tid = threadIdx.x;
    const float* Bz = BiasL + z * NOPEN;
    const ushort* Wz = Wt + (size_t)z * 9 * NHID * NOPEN;
    // staging: compute Znew rows [p0-4, p0+68), add bias, bf16 -> Xs
    for (int idx = tid; idx < 72 * 32; idx += 256) {
        int row = idx >> 5, ci = (idx & 31) * 4;
        int n = p0 - 4 + row;
        ushort4 o4 = {0, 0, 0, 0};
        if ((unsigned)n < (unsigned)NN) {
            float4 zc = *(const float4*)&Zc[n * 128 + ci];
            float4 zo = *(const float4*)&Zo[n * 128 + ci];
            float4 ta = *(const float4*)&Ta[n * 128 + ci];
            float4 bb = *(const float4*)&Bz[ci];
            o4.x = f2bf(2.f * zc.x - zo.x - H2 * ta.x + bb.x);
            o4.y = f2bf(2.f * zc.y - zo.y - H2 * ta.y + bb.y);
            o4.z = f2bf(2.f * zc.z - zo.z - H2 * ta.z + bb.z);
            o4.w = f2bf(2.f * zc.w - zo.w - H2 * ta.w + bb.w);
        }
        *(ushort4*)&Xs[row * 136 + ci] = o4;
    }
    for (int idx = tid; idx < 4608; idx += 256) {
        int t = idx >> 9, rem = idx & 511;
        int c = rem >> 4, ch = (rem & 15) * 8;
        *(bfrag*)&Wl[(t * 32 + c) * 136 + ch] = *(const bfrag*)&Wz[(t * NHID + co0 + c) * 128 + ch];
    }
    // Znew fp32 writeback (no bias), core rows only, 16 designated blocks
    if (blockIdx.y == 0 && z == 0) {
        for (int idx = tid; idx < 64 * 32; idx += 256) {
            int row = idx >> 5, ci = (idx & 31) * 4;
            int n = p0 + row;
            float4 zc = *(const float4*)&Zc[n * 128 + ci];
            float4 zo = *(const float4*)&Zo[n * 128 + ci];
            float4 ta = *(const float4*)&Ta[n * 128 + ci];
            float4 o;
            o.x = 2.f * zc.x - zo.x - H2 * ta.x;
            o.y = 2.f * zc.y - zo.y - H2 * ta.y;
            o.z = 2.f * zc.z - zo.z - H2 * ta.z;
            o.w = 2.f * zc.w - zo.w - H2 * ta.w;
            *(float4*)&Zn[n * 128 + ci] = o;
        }
    }
    __syncthreads();
    const int l = tid & 63, wv = tid >> 6;
    const int wm = wv >> 1, wn = wv & 1;
    const int lm = l & 15, lq = l >> 4;
    floatx4 acc[2] = {};
    for (int t = 0; t < 9; ++t) {
        const int wbase = (t * 32 + wm * 16 + lm) * 136 + lq * 8;
        const int xbase = (wn * 32 + lm + t) * 136 + lq * 8;
#pragma unroll
        for (int kc = 0; kc < 4; ++kc) {
            bfrag a = *(const bfrag*)&Wl[wbase + kc * 32];
            bfrag b0 = *(const bfrag*)&Xs[xbase + kc * 32];
            acc[0] = __builtin_amdgcn_mfma_f32_16x16x32_bf16(a, b0, acc[0], 0, 0, 0);
            bfrag b1 = *(const bfrag*)&Xs[xbase + 16 * 136 + kc * 32];
            acc[1] = __builtin_amdgcn_mfma_f32_16x16x32_bf16(a, b1, acc[1], 0, 0, 0);
        }
    }
    const int cog = co0 + wm * 16 + lq * 4;
    const int pg = p0 + wn * 32 + lm;
#pragma unroll
    for (int j = 0; j < 2; ++j)
#pragma unroll
        for (int r = 0; r < 4; ++r) {
            if (z == 0) C0[(cog + r) * NN + pg + j * 16] = acc[j][r];
            else        C1b[(cog + r) * NN + pg + j * 16] = f2bf(acc[j][r]);
        }
}

// ---------------- S2: xl1 split-8 (256 blocks) + normC0 per-channel (256 blocks) ----------------
__global__ __launch_bounds__(256) void k_s2(const ushort* __restrict__ C1b,
        const ushort* __restrict__ Lb, float* __restrict__ P1,
        const float* __restrict__ C0, ushort* __restrict__ At0) {
    __shared__ __align__(16) ushort sm[26112]; // As 64*136 + Bs 128*136
    const int bid = blockIdx.x, tid = threadIdx.x;
    if (bid < 256) {
        ushort* As = sm;
        ushort* Bs = sm + 8704;
        const int lane = tid & 63, wave = tid >> 6;
        const int wm = wave >> 1, wn = wave & 1;
        const int n0 = (bid & 7) * 128, m0 = ((bid >> 3) & 3) * 64, kc = (bid >> 5) * 128;
        int q = tid;
#pragma unroll
        for (int r = 0; r < 4; ++r, q += 256) {
            int row = q >> 4, ch = (q & 15) * 8;
            *(bfrag*)&As[row * 136 + ch] = *(const bfrag*)&C1b[(m0 + row) * NN + kc + ch];
        }
        q = tid;
#pragma unroll
        for (int r = 0; r < 8; ++r, q += 256) {
            int row = q >> 4, ch = (q & 15) * 8;
            *(bfrag*)&Bs[row * 136 + ch] = *(const bfrag*)&Lb[(n0 + row) * NN + kc + ch];
        }
        __syncthreads();
        floatx4 acc[2][4] = {};
        const int lrow = (lane & 15) * 136;
        const int koff = (lane >> 4) * 8;
#pragma unroll
        for (int ks = 0; ks < 4; ++ks) {
            bfrag a[2], b[4];
#pragma unroll
            for (int i = 0; i < 2; ++i)
                a[i] = *(const bfrag*)&As[(wm * 32 + i * 16) * 136 + lrow + ks * 32 + koff];
#pragma unroll
            for (int j = 0; j < 4; ++j)
                b[j] = *(const bfrag*)&Bs[(wn * 64 + j * 16) * 136 + lrow + ks * 32 + koff];
#pragma unroll
            for (int i = 0; i < 2; ++i)
#pragma unroll
                for (int j = 0; j < 4; ++j)
                    acc[i][j] = __builtin_amdgcn_mfma_f32_16x16x32_bf16(a[i], b[j], acc[i][j], 0, 0, 0);
        }
        const int mg0 = m0 + wm * 32 + (lane >> 4) * 4;
        const int ng0 = n0 + wn * 64 + (lane & 15);
        const size_t base = (size_t)(bid >> 5) * NHID * NN;
#pragma unroll
        for (int i = 0; i < 2; ++i)
#pragma unroll
            for (int j = 0; j < 4; ++j)
#pragma unroll
                for (int r = 0; r < 4; ++r)
                    P1[base + (size_t)(mg0 + i * 16 + r) * NN + ng0 + j * 16] = acc[i][j][r];
    } else {
        // normC0: one block per channel; stats + relu + bf16 + scattered transpose into At0
        float* rs = (float*)sm;
        float* rq = rs + 4;
        const int c = bid - 256;
        float4 v = *(const float4*)&C0[(size_t)c * NN + tid * 4];
        float s = (v.x + v.y) + (v.z + v.w);
        float qq = (v.x * v.x + v.y * v.y) + (v.z * v.z + v.w * v.w);
#pragma unroll
        for (int off = 32; off > 0; off >>= 1) { s += __shfl_down(s, off); qq += __shfl_down(qq, off); }
        if ((tid & 63) == 0) { rs[tid >> 6] = s; rq[tid >> 6] = qq; }
        __syncthreads();
        float S = rs[0] + rs[1] + rs[2] + rs[3];
        float Q = rq[0] + rq[1] + rq[2] + rq[3];
        float mean = S * (1.f / NN);
        float rstd = rsqrtf(Q * (1.f / NN) - mean * mean + IN_EPS);
        int p = tid * 4;
        At0[(p + 4) * 256 + c] = f2bf(fmaxf((v.x - mean) * rstd, 0.f));
        At0[(p + 5) * 256 + c] = f2bf(fmaxf((v.y - mean) * rstd, 0.f));
        At0[(p + 6) * 256 + c] = f2bf(fmaxf((v.z - mean) * rstd, 0.f));
        At0[(p + 7) * 256 + c] = f2bf(fmaxf((v.w - mean) * rstd, 0.f));
    }
}

// convT body (shared): computes 16ci x 64p tile for given z-source; returns acc + indices
__device__ __forceinline__ void convT_body(int b, const ushort* __restrict__ A,
        const ushort* __restrict__ Wz, ushort* sm, int tid, floatx4& acc, int& cig, int& pg) {
    const int pt = b & 15, cit = b >> 4;
    const int p0 = pt * 64, ci0 = cit * 16;
    ushort* Al = sm;             // 72*264
    ushort* Wl = sm + 19008;     // 9*16*264
    for (int idx = tid; idx < 2304; idx += 256) {
        int row = idx >> 5, ch = (idx & 31) * 8;
        *(bfrag*)&Al[row * 264 + ch] = *(const bfrag*)&A[(p0 + row) * 256 + ch];
    }
    for (int idx = tid; idx < 4608; idx += 256) {
        int t = idx >> 9, rem = idx & 511;
        int c = rem >> 5, ch = (rem & 31) * 8;
        *(bfrag*)&Wl[(t * 16 + c) * 264 + ch] = *(const bfrag*)&Wz[(t * NOPEN + ci0 + c) * 256 + ch];
    }
    __syncthreads();
    const int l = tid & 63, wv = tid >> 6;
    const int lm = l & 15, lq = l >> 4;
    floatx4 acc0 = {}, acc1 = {};
    for (int t = 0; t < 9; ++t) {
        const int abase = (wv * 16 + lm + 8 - t) * 264 + lq * 8;
        const int wbase = (t * 16 + lm) * 264 + lq * 8;
#pragma unroll
        for (int kc = 0; kc < 8; kc += 2) {
            bfrag a0 = *(const bfrag*)&Wl[wbase + kc * 32];
            bfrag b0 = *(const bfrag*)&Al[abase + kc * 32];
            acc0 = __builtin_amdgcn_mfma_f32_16x16x32_bf16(a0, b0, acc0, 0, 0, 0);
            bfrag a1 = *(const bfrag*)&Wl[wbase + kc * 32 + 32];
            bfrag b1 = *(const bfrag*)&Al[abase + kc * 32 + 32];
            acc1 = __builtin_amdgcn_mfma_f32_16x16x32_bf16(a1, b1, acc1, 0, 0, 0);
        }
    }
    acc = acc0 + acc1;
    cig = ci0 + lq * 4;
    pg = p0 + wv * 16 + lm;
}

// ---------------- S3: convT-z0 -> Tacc [n][ci] (128 blocks) + normA1 per-channel (256 blocks) ----------------
__global__ __launch_bounds__(256) void k_s3(const ushort* __restrict__ At0,
        const ushort* __restrict__ WtT, float* __restrict__ Tacc,
        const float* __restrict__ P1, ushort* __restrict__ At1) {
    __shared__ __align__(16) ushort sm[57024];
    const int bid = blockIdx.x, tid = threadIdx.x;
    if (bid < 128) {
        floatx4 acc; int cig, pg;
        convT_body(bid, At0, WtT, sm, tid, acc, cig, pg);
#pragma unroll
        for (int r = 0; r < 4; ++r)
            Tacc[pg * 128 + cig + r] = acc[r];
    } else {
        float* rs = (float*)sm;
        float* rq = rs + 4;
        const int c = bid - 128;
        float4 v = {0.f, 0.f, 0.f, 0.f};
#pragma unroll
        for (int s = 0; s < 8; ++s) {
            float4 p = *(const float4*)&P1[(size_t)(s * NHID + c) * NN + tid * 4];
            v.x += p.x; v.y += p.y; v.z += p.z; v.w += p.w;
        }
        float s = (v.x + v.y) + (v.z + v.w);
        float qq = (v.x * v.x + v.y * v.y) + (v.z * v.z + v.w * v.w);
#pragma unroll
        for (int off = 32; off > 0; off >>= 1) { s += __shfl_down(s, off); qq += __shfl_down(qq, off); }
        if ((tid & 63) == 0) { rs[tid >> 6] = s; rq[tid >> 6] = qq; }
        __syncthreads();
        float S = rs[0] + rs[1] + rs[2] + rs[3];
        float Q = rq[0] + rq[1] + rq[2] + rq[3];
        float mean = S * (1.f / NN);
        float rstd = rsqrtf(Q * (1.f / NN) - mean * mean + IN_EPS);
        int p = tid * 4;
        At1[(p + 4) * 256 + c] = f2bf(fmaxf((v.x - mean) * rstd, 0.f));
        At1[(p + 5) * 256 + c] = f2bf(fmaxf((v.y - mean) * rstd, 0.f));
        At1[(p + 6) * 256 + c] = f2bf(fmaxf((v.z - mean) * rstd, 0.f));
        At1[(p + 7) * 256 + c] = f2bf(fmaxf((v.w - mean) * rstd, 0.f));
    }
}

// ---------------- S4: convT-z1 -> T1b [ci][n] (128 blocks) + prepw next (144 blocks) ----------------
__global__ __launch_bounds__(256) void k_s4(const ushort* __restrict__ At1,
        const ushort* __restrict__ WtT, ushort* __restrict__ T1b,
        const float* __restrict__ W, ushort* __restrict__ Wt, ushort* __restrict__ WtT_w,
        int lnext, int doprep) {
    __shared__ __align__(16) ushort sm[57024];
    const int bid = blockIdx.x, tid = threadIdx.x;
    if (bid < 128) {
        floatx4 acc; int cig, pg;
        convT_body(bid, At1, WtT + (size_t)9 * NOPEN * NHID, sm, tid, acc, cig, pg);
#pragma unroll
        for (int r = 0; r < 4; ++r)
            T1b[(cig + r) * NN + pg] = f2bf(acc[r]);
    } else {
        if (doprep) prepw_piece(W, Wt, WtT_w, bid - 128, lnext, tid);
    }
}

// ---------------- S5: xl2 split-8, atomicAdd into Tacc [n][ci] (128 blocks) + sig=0 ----------------
__global__ __launch_bounds__(256) void k_s5(const ushort* __restrict__ T1b,
        const ushort* __restrict__ Lb, float* __restrict__ Tacc, float* __restrict__ sig) {
    __shared__ __align__(16) ushort sm[26112];
    const int bid = blockIdx.x, tid = threadIdx.x;
    if (bid < 128) {
        ushort* As = sm;
        ushort* Bs = sm + 8704;
        const int lane = tid & 63, wave = tid >> 6;
        const int wm = wave >> 1, wn = wave & 1;
        const int n0 = (bid & 7) * 128, m0 = ((bid >> 3) & 1) * 64, kc = (bid >> 4) * 128;
        int q = tid;
#pragma unroll
        for (int r = 0; r < 4; ++r, q += 256) {
            int row = q >> 4, ch = (q & 15) * 8;
            *(bfrag*)&As[row * 136 + ch] = *(const bfrag*)&T1b[(m0 + row) * NN + kc + ch];
        }
        q = tid;
#pragma unroll
        for (int r = 0; r < 8; ++r, q += 256) {
            int row = q >> 4, ch = (q & 15) * 8;
            *(bfrag*)&Bs[row * 136 + ch] = *(const bfrag*)&Lb[(n0 + row) * NN + kc + ch];
        }
        __syncthreads();
        floatx4 acc[2][4] = {};
        const int lrow = (lane & 15) * 136;
        const int koff = (lane >> 4) * 8;
#pragma unroll
        for (int ks = 0; ks < 4; ++ks) {
            bfrag a[2], b[4];
#pragma unroll
            for (int i = 0; i < 2; ++i)
                a[i] = *(const bfrag*)&As[(wm * 32 + i * 16) * 136 + lrow + ks * 32 + koff];
#pragma unroll
            for (int j = 0; j < 4; ++j)
                b[j] = *(const bfrag*)&Bs[(wn * 64 + j * 16) * 136 + lrow + ks * 32 + koff];
#pragma unroll
            for (int i = 0; i < 2; ++i)
#pragma unroll
                for (int j = 0; j < 4; ++j)
                    acc[i][j] = __builtin_amdgcn_mfma_f32_16x16x32_bf16(a[i], b[j], acc[i][j], 0, 0, 0);
        }
        const int mg0 = m0 + wm * 32 + (lane >> 4) * 4;
        const int ng0 = n0 + wn * 64 + (lane & 15);
#pragma unroll
        for (int i = 0; i < 2; ++i)
#pragma unroll
            for (int j = 0; j < 4; ++j)
#pragma unroll
                for (int r = 0; r < 4; ++r)
                    atomicAdd(&Tacc[(ng0 + j * 16) * 128 + mg0 + i * 16 + r], acc[i][j][r]);
    } else {
        if (tid == 0) sig[0] = 0.f;
    }
}

// ---------------- closing: out0 = Kclose @ (2Zc - Zo - H2*Tacc), out1 = Kclose @ Zc ----------------
__global__ void k_close(const float* __restrict__ Kclose, const float* __restrict__ Zc,
                        const float* __restrict__ Zo, const float* __restrict__ Ta,
                        float* __restrict__ out) {
    int n = blockIdx.x * 256 + threadIdx.x;
    int o = blockIdx.y, zsel = blockIdx.z;
    float a = 0.f;
    if (zsel == 0) {
#pragma unroll
        for (int c4 = 0; c4 < 32; ++c4) {
            float4 zc = *(const float4*)&Zc[n * 128 + c4 * 4];
            float4 zo = *(const float4*)&Zo[n * 128 + c4 * 4];
            float4 ta = *(const float4*)&Ta[n * 128 + c4 * 4];
            float4 k = *(const float4*)&Kclose[o * 128 + c4 * 4];
            a = fmaf(k.x, 2.f * zc.x - zo.x - H2 * ta.x, a);
            a = fmaf(k.y, 2.f * zc.y - zo.y - H2 * ta.y, a);
            a = fmaf(k.z, 2.f * zc.z - zo.z - H2 * ta.z, a);
            a = fmaf(k.w, 2.f * zc.w - zo.w - H2 * ta.w, a);
        }
    } else {
#pragma unroll
        for (int c4 = 0; c4 < 32; ++c4) {
            float4 zc = *(const float4*)&Zc[n * 128 + c4 * 4];
            float4 k = *(const float4*)&Kclose[o * 128 + c4 * 4];
            a = fmaf(k.x, zc.x, a); a = fmaf(k.y, zc.y, a);
            a = fmaf(k.z, zc.z, a); a = fmaf(k.w, zc.w, a);
        }
    }
    out[zsel * (NCLOSE * NN) + o * NN + n] = a;
}

extern "C" void kernel_launch(void* const* d_in, const int* in_sizes, int n_in,
                              void* d_out, int out_size, void* d_ws, size_t ws_size,
                              hipStream_t stream) {
    const float* Z      = (const float*)d_in[0];
    const float* Kopen  = (const float*)d_in[1];
    const float* Kclose = (const float*)d_in[2];
    const float* W      = (const float*)d_in[3];
    const float* Bias   = (const float*)d_in[4];
    float* out = (float*)d_out;
    float* ws  = (float*)d_ws;

    // workspace layout (float units); state arrays are [n][ci]
    float* B0   = ws + 0;         // 131072
    float* B1   = ws + 131072;    // 131072
    float* B2   = ws + 262144;    // 131072
    float* Tacc = ws + 393216;    // 131072
    float* D2   = ws + 524288;    // 1048576
    float* C0   = ws + 1572864;   // 262144
    float* P1   = ws + 1835008;   // 2097152
    float* Dh   = ws + 3932160;   // 1024
    float* sig  = ws + 3933184;   // 1024
    ushort* Lb  = (ushort*)(ws + 3934208); // 1048576 us
    ushort* C1b = (ushort*)(ws + 4458496); // 262144 us
    ushort* T1b = (ushort*)(ws + 4589568); // 131072 us
    ushort* At0 = (ushort*)(ws + 4655104); // 1032*256 us
    ushort* At1 = (ushort*)(ws + 4787200); // 1032*256 us
    ushort* Wt  = (ushort*)(ws + 4919296); // 2*9*256*128 us
    ushort* WtT = (ushort*)(ws + 5214208); // 2*9*128*256 us (end 5509120 floats = 22 MB)

    k_open<<<dim3(785), 256, 0, stream>>>(Kopen, Z, B0, At0, At1, W, Wt, WtT, Tacc, sig);

    // triple-buffer state: conv of iter l reads (Zc_{l-1}, Zo_{l-1}, Tacc_{l-1}) -> Zn = Zc_l
    float* bufs[3] = {B0, B1, B2};
    int ic = 0, io = 0; // layer -1: Zc == Zo == B0, Tacc = 0 -> Znew = Zc
    for (int l = 0; l < NLAYERS; ++l) {
        int in_ = 3 - ((ic == io) ? (ic + ic) % 3 : (ic + io))
                  ; // free buffer index: the one not in {ic, io}
        if (ic == io) in_ = (ic + 1) % 3;
        else in_ = 3 - ic - io;
        float* Zc = bufs[ic];
        float* Zo = bufs[io];
        float* Zn = bufs[in_];

        k_conv2<<<dim3(16, 8, 2), 256, 0, stream>>>(Zc, Zo, Tacc, Zn,
                Bias + (size_t)l * 2 * NOPEN, Wt, C0, C1b);
        if (l % 10 == 0) {
            k_d2<<<dim3(16, 32), 256, 0, stream>>>(Zn, D2, sig);
            k_deg<<<dim3(NN), 256, 0, stream>>>(D2, sig, Dh);
            k_L<<<dim3(NN), 256, 0, stream>>>(D2, sig, Dh, Lb);
        }
        k_s2<<<dim3(512), 256, 0, stream>>>(C1b, Lb, P1, C0, At0);
        k_s3<<<dim3(384), 256, 0, stream>>>(At0, WtT, Tacc, P1, At1);
        int lnext = (l + 1 < NLAYERS) ? l + 1 : l;
        k_s4<<<dim3(272), 256, 0, stream>>>(At1, WtT, T1b, W, Wt, WtT,
                                            lnext, (l + 1 < NLAYERS) ? 1 : 0);
        k_s5<<<dim3(129), 256, 0, stream>>>(T1b, Lb, Tacc, sig);
        // rotate: Zc_l = Zn; Zold_l = Zc_{l-1}
        io = ic; ic = in_;
    }
    // final: out0 = K @ (2*Zc_39 - Zold_39 - H2*F_39), out1 = K @ Zc_39
    k_close<<<dim3(4, NCLOSE, 2), 256, 0, stream>>>(Kclose, bufs[ic], bufs[io], Tacc, out);
}

// Round 8
// 2452.275 us; speedup vs baseline: 1.1808x; 1.1808x over previous
//
#include <hip/hip_runtime.h>

#define NN 1024
#define NOPEN 128
#define NHID 256
#define NSTART 40
#define NCLOSE 3
#define NLAYERS 40
#define KSZ 9

static constexpr float H2 = 0.01f;     // h*h, h = 0.1
static constexpr float IN_EPS = 1e-5f; // instance norm eps

using floatx4 = __attribute__((ext_vector_type(4))) float;
using bfrag = __attribute__((ext_vector_type(8))) short; // 8 bf16 = 4 VGPRs

__device__ __forceinline__ ushort f2bf(float f) {
    union { float f; unsigned u; } v; v.f = f;
    unsigned r = v.u + 0x7fffu + ((v.u >> 16) & 1u); // RNE
    return (ushort)(r >> 16);
}

// weight transpose prep: lb<72 -> Wt[z][t][co][ci]; else WtT[z][t][ci][co]
__device__ __forceinline__ void prepw_piece(const float* __restrict__ W, ushort* __restrict__ Wt,
                                            ushort* __restrict__ WtT, int lb, int lsrc, int tid) {
    if (lb < 72) {
        int q = lb; int coq = q & 3; q >>= 2; int t = q % 9, z = q / 9;
        const float* Wz = W + (size_t)(lsrc * 2 + z) * (NHID * NOPEN * KSZ);
        ushort* Wo = Wt + ((size_t)z * 9 + t) * (NHID * NOPEN);
#pragma unroll
        for (int r = 0; r < 32; ++r) {
            int idx = r * 256 + tid;
            int co = coq * 64 + (idx >> 7), ci = idx & 127;
            Wo[co * NOPEN + ci] = f2bf(Wz[co * (NOPEN * KSZ) + ci * KSZ + t]);
        }
    } else {
        int q = lb - 72; int ciq = q & 3; q >>= 2; int t = q % 9, z = q / 9;
        const float* Wz = W + (size_t)(lsrc * 2 + z) * (NHID * NOPEN * KSZ);
        ushort* Wo = WtT + ((size_t)z * 9 + t) * (NOPEN * NHID);
#pragma unroll
        for (int r = 0; r < 32; ++r) {
            int idx = r * 256 + tid;
            int ci = ciq * 32 + (idx >> 8), co = idx & 255;
            Wo[ci * NHID + co] = f2bf(Wz[co * (NOPEN * KSZ) + ci * KSZ + t]);
        }
    }
}

// ---------------- opening: Zc/Zold/Zct(layer0) + weight prep(layer0) + pads + sig=0 ----------------
__global__ __launch_bounds__(256) void k_open(const float* __restrict__ Kopen, const float* __restrict__ Z,
                       float* __restrict__ Zc, float* __restrict__ Zold,
                       const float* __restrict__ Bias0, ushort* __restrict__ Zct,
                       ushort* __restrict__ At0, ushort* __restrict__ At1,
                       const float* __restrict__ W, ushort* __restrict__ Wt,
                       ushort* __restrict__ WtT, float* __restrict__ sig) {
    const int v = blockIdx.x, tid = threadIdx.x;
    if (v < 512) {
        int o = v >> 2, n = (v & 3) * 256 + tid;
        float acc = 0.f;
#pragma unroll
        for (int s = 0; s < NSTART; ++s)
            acc = fmaf(Kopen[o * NSTART + s], Z[s * NN + n], acc);
        Zc[o * NN + n] = acc;
        Zold[o * NN + n] = acc;
#pragma unroll
        for (int z = 0; z < 2; ++z)
            Zct[z * (1032 * 128) + (n + 4) * 128 + o] = f2bf(acc + Bias0[z * NOPEN + o]);
    } else if (v < 656) {
        prepw_piece(W, Wt, WtT, v - 512, 0, tid);
    } else {
        if (tid == 0) sig[0] = 0.f;
        for (int idx = tid; idx < 1024; idx += 256) {
            int z = idx >> 9, rr = idx & 511;
            ushort* Zz = Zct + z * (1032 * 128);
            Zz[rr] = 0; Zz[1028 * 128 + rr] = 0;
        }
        for (int idx = tid; idx < 2048; idx += 256) {
            int a = idx >> 10, rr = idx & 1023;
            ushort* A = a ? At1 : At0;
            A[rr] = 0; A[1028 * 256 + rr] = 0;
        }
    }
}

// ---------------- D2 = max(sq_i + sq_j - 2 Z^T Z, 0); sq in-block; sum(D2) -> sig ----------------
__global__ __launch_bounds__(256) void k_d2(const float* __restrict__ Zc,
                                            float* __restrict__ D2, float* __restrict__ sig) {
    __shared__ __align__(16) float Zi[32 * 36];
    __shared__ __align__(16) float Zj[32 * 68];
    __shared__ float sqi[32], sqj[64];
    __shared__ float red[4];
    const int tid = threadIdx.x;
    const int tx = tid & 15, ty = tid >> 4;
    const int j0 = blockIdx.x * 64, i0 = blockIdx.y * 32;
    if (tid < 32) sqi[tid] = 0.f;
    else if (tid < 96) sqj[tid - 32] = 0.f;
    float acc[2][4] = {};
    for (int c0 = 0; c0 < NOPEN; c0 += 32) {
        for (int idx = tid; idx < 32 * 32; idx += 256) {
            int c = idx >> 5, ii = idx & 31;
            Zi[c * 36 + ii] = Zc[(c0 + c) * NN + i0 + ii];
        }
        for (int idx = tid; idx < 32 * 64; idx += 256) {
            int c = idx >> 6, jj = idx & 63;
            Zj[c * 68 + jj] = Zc[(c0 + c) * NN + j0 + jj];
        }
        __syncthreads();
        if (tid < 32) {
            float s = 0.f;
            for (int c = 0; c < 32; ++c) { float x = Zi[c * 36 + tid]; s = fmaf(x, x, s); }
            sqi[tid] += s;
        } else if (tid < 96) {
            int jj = tid - 32;
            float s = 0.f;
            for (int c = 0; c < 32; ++c) { float x = Zj[c * 68 + jj]; s = fmaf(x, x, s); }
            sqj[jj] += s;
        }
#pragma unroll 8
        for (int c = 0; c < 32; ++c) {
            float2 zi = *(const float2*)&Zi[c * 36 + ty * 2];
            float4 zj = *(const float4*)&Zj[c * 68 + tx * 4];
            acc[0][0] = fmaf(zi.x, zj.x, acc[0][0]);
            acc[0][1] = fmaf(zi.x, zj.y, acc[0][1]);
            acc[0][2] = fmaf(zi.x, zj.z, acc[0][2]);
            acc[0][3] = fmaf(zi.x, zj.w, acc[0][3]);
            acc[1][0] = fmaf(zi.y, zj.x, acc[1][0]);
            acc[1][1] = fmaf(zi.y, zj.y, acc[1][1]);
            acc[1][2] = fmaf(zi.y, zj.z, acc[1][2]);
            acc[1][3] = fmaf(zi.y, zj.w, acc[1][3]);
        }
        __syncthreads();
    }
    float part = 0.f;
#pragma unroll
    for (int m = 0; m < 2; ++m) {
        int i = i0 + ty * 2 + m;
        float sqi_v = sqi[ty * 2 + m];
        float4 d;
        d.x = fmaxf(sqi_v + sqj[tx * 4 + 0] - 2.f * acc[m][0], 0.f);
        d.y = fmaxf(sqi_v + sqj[tx * 4 + 1] - 2.f * acc[m][1], 0.f);
        d.z = fmaxf(sqi_v + sqj[tx * 4 + 2] - 2.f * acc[m][2], 0.f);
        d.w = fmaxf(sqi_v + sqj[tx * 4 + 3] - 2.f * acc[m][3], 0.f);
        *(float4*)&D2[(size_t)i * NN + j0 + tx * 4] = d;
        part += (d.x + d.y) + (d.z + d.w);
    }
#pragma unroll
    for (int off = 32; off > 0; off >>= 1) part += __shfl_down(part, off);
    if ((tid & 63) == 0) red[tid >> 6] = part;
    __syncthreads();
    if (tid == 0) atomicAdd(sig, red[0] + red[1] + red[2] + red[3]);
}

// ---------------- deg / L ----------------
__global__ void k_deg(const float* __restrict__ D2, const float* __restrict__ sig,
                      float* __restrict__ Dh) {
    __shared__ float red[4];
    int i = blockIdx.x, tid = threadIdx.x;
    float inv = 1.f / (sig[0] * (1.f / 1048576.f) + 1e-12f);
    float4 v = *(const float4*)&D2[(size_t)i * NN + tid * 4];
    float s = __expf(-v.x * inv) + __expf(-v.y * inv) + __expf(-v.z * inv) + __expf(-v.w * inv);
#pragma unroll
    for (int off = 32; off > 0; off >>= 1) s += __shfl_down(s, off);
    if ((tid & 63) == 0) red[tid >> 6] = s;
    __syncthreads();
    if (tid == 0) Dh[i] = rsqrtf(red[0] + red[1] + red[2] + red[3]);
}

__global__ void k_L(const float* __restrict__ D2, const float* __restrict__ sig,
                    const float* __restrict__ Dh, ushort* __restrict__ Lb) {
    int i = blockIdx.x, tid = threadIdx.x;
    int j = tid * 4;
    float inv = 1.f / (sig[0] * (1.f / 1048576.f) + 1e-12f);
    float dhi = Dh[i];
    float4 v = *(const float4*)&D2[(size_t)i * NN + j];
    float4 dj = *(const float4*)&Dh[j];
    float4 o;
    o.x = -dhi * dj.x * __expf(-v.x * inv);
    o.y = -dhi * dj.y * __expf(-v.y * inv);
    o.z = -dhi * dj.z * __expf(-v.z * inv);
    o.w = -dhi * dj.w * __expf(-v.w * inv);
    if (i == j + 0) o.x += 1.f;
    if (i == j + 1) o.y += 1.f;
    if (i == j + 2) o.z += 1.f;
    if (i == j + 3) o.w += 1.f;
    ushort4 ob; ob.x = f2bf(o.x); ob.y = f2bf(o.y); ob.z = f2bf(o.z); ob.w = f2bf(o.w);
    *(ushort4*)&Lb[(size_t)i * NN + j] = ob;
}

// ---------------- MFMA conv1d (round-6 body): grid (16 p, 8 co, 2 z) ----------------
__global__ __launch_bounds__(256) void k_conv(const ushort* __restrict__ Zct,
        const ushort* __restrict__ Wt, float* __restrict__ C0, ushort* __restrict__ C1b) {
    const int z = blockIdx.z;
    const int p0 = blockIdx.x * 64, co0 = blockIdx.y * 32;
    __shared__ ushort Xs[72 * 136];
    __shared__ ushort Wl[9 * 32 * 136];
    const int tid = threadIdx.x;
    const ushort* Zz = Zct + z * (1032 * 128);
    const ushort* Wz = Wt + (size_t)z * 9 * NHID * NOPEN;
    for (int idx = tid; idx < 1152; idx += 256) {
        int row = idx >> 4, ch = (idx & 15) * 8;
        *(bfrag*)&Xs[row * 136 + ch] = *(const bfrag*)&Zz[(p0 + row) * 128 + ch];
    }
    for (int idx = tid; idx < 4608; idx += 256) {
        int t = idx >> 9, rem = idx & 511;
        int c = rem >> 4, ch = (rem & 15) * 8;
        *(bfrag*)&Wl[(t * 32 + c) * 136 + ch] = *(const bfrag*)&Wz[(t * NHID + co0 + c) * 128 + ch];
    }
    __syncthreads();
    const int l = tid & 63, wv = tid >> 6;
    const int wm = wv >> 1, wn = wv & 1;
    const int lm = l & 15, lq = l >> 4;
    floatx4 acc[2] = {};
    for (int t = 0; t < 9; ++t) {
        const int wbase = (t * 32 + wm * 16 + lm) * 136 + lq * 8;
        const int xbase = (wn * 32 + lm + t) * 136 + lq * 8;
#pragma unroll
        for (int kc = 0; kc < 4; ++kc) {
            bfrag a = *(const bfrag*)&Wl[wbase + kc * 32];
            bfrag b0 = *(const bfrag*)&Xs[xbase + kc * 32];
            acc[0] = __builtin_amdgcn_mfma_f32_16x16x32_bf16(a, b0, acc[0], 0, 0, 0);
            bfrag b1 = *(const bfrag*)&Xs[xbase + 16 * 136 + kc * 32];
            acc[1] = __builtin_amdgcn_mfma_f32_16x16x32_bf16(a, b1, acc[1], 0, 0, 0);
        }
    }
    const int cog = co0 + wm * 16 + lq * 4;
    const int pg = p0 + wn * 32 + lm;
#pragma unroll
    for (int j = 0; j < 2; ++j)
#pragma unroll
        for (int r = 0; r < 4; ++r) {
            if (z == 0) C0[(cog + r) * NN + pg + j * 16] = acc[j][r];
            else        C1b[(cog + r) * NN + pg + j * 16] = f2bf(acc[j][r]);
        }
}

// xl split-8 body (round-6 k_xl_mfma), parameterized by flat block id
__device__ __forceinline__ void xl_body(int bid, const ushort* __restrict__ X,
        const ushort* __restrict__ Lb, float* __restrict__ P, int M, int mt_bits,
        ushort* sm, int tid) {
    ushort* As = sm;           // 64*136
    ushort* Bs = sm + 8704;    // 128*136
    const int lane = tid & 63, wave = tid >> 6;
    const int wm = wave >> 1, wn = wave & 1;
    const int n0 = (bid & 7) * 128;
    const int m0 = ((bid >> 3) & ((1 << mt_bits) - 1)) * 64;
    const int ksp = bid >> (3 + mt_bits);
    const int kc = ksp * 128;
    int q = tid;
#pragma unroll
    for (int r = 0; r < 4; ++r, q += 256) {
        int row = q >> 4, ch = (q & 15) * 8;
        *(bfrag*)&As[row * 136 + ch] = *(const bfrag*)&X[(m0 + row) * NN + kc + ch];
    }
    q = tid;
#pragma unroll
    for (int r = 0; r < 8; ++r, q += 256) {
        int row = q >> 4, ch = (q & 15) * 8;
        *(bfrag*)&Bs[row * 136 + ch] = *(const bfrag*)&Lb[(n0 + row) * NN + kc + ch];
    }
    __syncthreads();
    floatx4 acc[2][4] = {};
    const int lrow = (lane & 15) * 136;
    const int koff = (lane >> 4) * 8;
#pragma unroll
    for (int ks = 0; ks < 4; ++ks) {
        bfrag a[2], b[4];
#pragma unroll
        for (int i = 0; i < 2; ++i)
            a[i] = *(const bfrag*)&As[(wm * 32 + i * 16) * 136 + lrow + ks * 32 + koff];
#pragma unroll
        for (int j = 0; j < 4; ++j)
            b[j] = *(const bfrag*)&Bs[(wn * 64 + j * 16) * 136 + lrow + ks * 32 + koff];
#pragma unroll
        for (int i = 0; i < 2; ++i)
#pragma unroll
            for (int j = 0; j < 4; ++j)
                acc[i][j] = __builtin_amdgcn_mfma_f32_16x16x32_bf16(a[i], b[j], acc[i][j], 0, 0, 0);
    }
    const int mg0 = m0 + wm * 32 + (lane >> 4) * 4;
    const int ng0 = n0 + wn * 64 + (lane & 15);
    const size_t base = (size_t)ksp * M * NN;
#pragma unroll
    for (int i = 0; i < 2; ++i)
#pragma unroll
        for (int j = 0; j < 4; ++j)
#pragma unroll
            for (int r = 0; r < 4; ++r)
                P[base + (size_t)(mg0 + i * 16 + r) * NN + ng0 + j * 16] = acc[i][j][r];
}

// ---------------- S2: xl1 split-8 (256 blk) + normC0 per-channel (256 blk) ----------------
__global__ __launch_bounds__(256) void k_s2(const ushort* __restrict__ C1b,
        const ushort* __restrict__ Lb, float* __restrict__ P1,
        const float* __restrict__ C0, ushort* __restrict__ At0) {
    __shared__ __align__(16) ushort sm[26112];
    const int bid = blockIdx.x, tid = threadIdx.x;
    if (bid < 256) {
        xl_body(bid, C1b, Lb, P1, NHID, 2, sm, tid);
    } else {
        float* rs = (float*)sm;
        float* rq = rs + 4;
        const int c = bid - 256;
        float4 v = *(const float4*)&C0[(size_t)c * NN + tid * 4];
        float s = (v.x + v.y) + (v.z + v.w);
        float qq = (v.x * v.x + v.y * v.y) + (v.z * v.z + v.w * v.w);
#pragma unroll
        for (int off = 32; off > 0; off >>= 1) { s += __shfl_down(s, off); qq += __shfl_down(qq, off); }
        if ((tid & 63) == 0) { rs[tid >> 6] = s; rq[tid >> 6] = qq; }
        __syncthreads();
        float S = rs[0] + rs[1] + rs[2] + rs[3];
        float Q = rq[0] + rq[1] + rq[2] + rq[3];
        float mean = S * (1.f / NN);
        float rstd = rsqrtf(Q * (1.f / NN) - mean * mean + IN_EPS);
        int p = tid * 4;
        At0[(p + 4) * 256 + c] = f2bf(fmaxf((v.x - mean) * rstd, 0.f));
        At0[(p + 5) * 256 + c] = f2bf(fmaxf((v.y - mean) * rstd, 0.f));
        At0[(p + 6) * 256 + c] = f2bf(fmaxf((v.z - mean) * rstd, 0.f));
        At0[(p + 7) * 256 + c] = f2bf(fmaxf((v.w - mean) * rstd, 0.f));
    }
}

// convT body (round-6): 16ci x 64p tile
__device__ __forceinline__ void convT_body(int b, const ushort* __restrict__ A,
        const ushort* __restrict__ Wz, ushort* sm, int tid, floatx4& acc, int& cig, int& pg) {
    const int pt = b & 15, cit = b >> 4;
    const int p0 = pt * 64, ci0 = cit * 16;
    ushort* Al = sm;             // 72*264
    ushort* Wl = sm + 19008;     // 9*16*264
    for (int idx = tid; idx < 2304; idx += 256) {
        int row = idx >> 5, ch = (idx & 31) * 8;
        *(bfrag*)&Al[row * 264 + ch] = *(const bfrag*)&A[(p0 + row) * 256 + ch];
    }
    for (int idx = tid; idx < 4608; idx += 256) {
        int t = idx >> 9, rem = idx & 511;
        int c = rem >> 5, ch = (rem & 31) * 8;
        *(bfrag*)&Wl[(t * 16 + c) * 264 + ch] = *(const bfrag*)&Wz[(t * NOPEN + ci0 + c) * 256 + ch];
    }
    __syncthreads();
    const int l = tid & 63, wv = tid >> 6;
    const int lm = l & 15, lq = l >> 4;
    floatx4 acc0 = {}, acc1 = {};
    for (int t = 0; t < 9; ++t) {
        const int abase = (wv * 16 + lm + 8 - t) * 264 + lq * 8;
        const int wbase = (t * 16 + lm) * 264 + lq * 8;
#pragma unroll
        for (int kc = 0; kc < 8; kc += 2) {
            bfrag a0 = *(const bfrag*)&Wl[wbase + kc * 32];
            bfrag b0 = *(const bfrag*)&Al[abase + kc * 32];
            acc0 = __builtin_amdgcn_mfma_f32_16x16x32_bf16(a0, b0, acc0, 0, 0, 0);
            bfrag a1 = *(const bfrag*)&Wl[wbase + kc * 32 + 32];
            bfrag b1 = *(const bfrag*)&Al[abase + kc * 32 + 32];
            acc1 = __builtin_amdgcn_mfma_f32_16x16x32_bf16(a1, b1, acc1, 0, 0, 0);
        }
    }
    acc = acc0 + acc1;
    cig = ci0 + lq * 4;
    pg = p0 + wv * 16 + lm;
}

// ---------------- S3: convT-z0 -> Tacc (128 blk) + normA1 (256 blk) ----------------
__global__ __launch_bounds__(256) void k_s3(const ushort* __restrict__ At0,
        const ushort* __restrict__ WtT, float* __restrict__ Tacc,
        const float* __restrict__ P1, ushort* __restrict__ At1) {
    __shared__ __align__(16) ushort sm[57024];
    const int bid = blockIdx.x, tid = threadIdx.x;
    if (bid < 128) {
        floatx4 acc; int cig, pg;
        convT_body(bid, At0, WtT, sm, tid, acc, cig, pg);
#pragma unroll
        for (int r = 0; r < 4; ++r)
            Tacc[(cig + r) * NN + pg] = acc[r];
    } else {
        float* rs = (float*)sm;
        float* rq = rs + 4;
        const int c = bid - 128;
        float4 v = {0.f, 0.f, 0.f, 0.f};
#pragma unroll
        for (int s = 0; s < 8; ++s) {
            float4 p = *(const float4*)&P1[(size_t)(s * NHID + c) * NN + tid * 4];
            v.x += p.x; v.y += p.y; v.z += p.z; v.w += p.w;
        }
        float s = (v.x + v.y) + (v.z + v.w);
        float qq = (v.x * v.x + v.y * v.y) + (v.z * v.z + v.w * v.w);
#pragma unroll
        for (int off = 32; off > 0; off >>= 1) { s += __shfl_down(s, off); qq += __shfl_down(qq, off); }
        if ((tid & 63) == 0) { rs[tid >> 6] = s; rq[tid >> 6] = qq; }
        __syncthreads();
        float S = rs[0] + rs[1] + rs[2] + rs[3];
        float Q = rq[0] + rq[1] + rq[2] + rq[3];
        float mean = S * (1.f / NN);
        float rstd = rsqrtf(Q * (1.f / NN) - mean * mean + IN_EPS);
        int p = tid * 4;
        At1[(p + 4) * 256 + c] = f2bf(fmaxf((v.x - mean) * rstd, 0.f));
        At1[(p + 5) * 256 + c] = f2bf(fmaxf((v.y - mean) * rstd, 0.f));
        At1[(p + 6) * 256 + c] = f2bf(fmaxf((v.z - mean) * rstd, 0.f));
        At1[(p + 7) * 256 + c] = f2bf(fmaxf((v.w - mean) * rstd, 0.f));
    }
}

// ---------------- S4: convT-z1 -> T1b bf16 (128 blk) ----------------
__global__ __launch_bounds__(256) void k_s4(const ushort* __restrict__ At1,
        const ushort* __restrict__ WtT, ushort* __restrict__ T1b) {
    __shared__ __align__(16) ushort sm[57024];
    const int bid = blockIdx.x, tid = threadIdx.x;
    floatx4 acc; int cig, pg;
    convT_body(bid, At1, WtT + (size_t)9 * NOPEN * NHID, sm, tid, acc, cig, pg);
#pragma unroll
    for (int r = 0; r < 4; ++r)
        T1b[(cig + r) * NN + pg] = f2bf(acc[r]);
}

// ---------------- S5: xl2 split-8 -> P2 (128 blk) + prepw next (144 blk) + sig=0 ----------------
// no weight readers in this dispatch -> prepw is race-free
__global__ __launch_bounds__(256) void k_s5(const ushort* __restrict__ T1b,
        const ushort* __restrict__ Lb, float* __restrict__ P2,
        const float* __restrict__ W, ushort* __restrict__ Wt, ushort* __restrict__ WtT,
        float* __restrict__ sig, int lnext, int doprep) {
    __shared__ __align__(16) ushort sm[26112];
    const int bid = blockIdx.x, tid = threadIdx.x;
    if (bid < 128) {
        xl_body(bid, T1b, Lb, P2, NOPEN, 1, sm, tid);
    } else if (bid < 272) {
        if (doprep) prepw_piece(W, Wt, WtT, bid - 128, lnext, tid);
    } else {
        if (tid == 0) sig[0] = 0.f;
    }
}

// ---------------- leapfrog (round-6 body): sum Tacc + 8 P2 partials, write Zo + next Zct ----------------
__global__ __launch_bounds__(256) void k_leap(const float* __restrict__ P2,
        const float* __restrict__ Tacc, const float* __restrict__ Zc, float* __restrict__ Zo,
        const float* __restrict__ BiasN, ushort* __restrict__ Zct) {
    const int v = blockIdx.x, tid = threadIdx.x;
    int off = (v * 256 + tid) * 4;
    float4 a = *(const float4*)&Tacc[off];
#pragma unroll
    for (int s = 0; s < 8; ++s) {
        float4 p = *(const float4*)&P2[(size_t)(s << 17) + off];
        a.x += p.x; a.y += p.y; a.z += p.z; a.w += p.w;
    }
    float4 zc = *(const float4*)&Zc[off];
    float4 zo = *(const float4*)&Zo[off];
    float4 zn;
    zn.x = 2.f * zc.x - zo.x - H2 * a.x;
    zn.y = 2.f * zc.y - zo.y - H2 * a.y;
    zn.z = 2.f * zc.z - zo.z - H2 * a.z;
    zn.w = 2.f * zc.w - zo.w - H2 * a.w;
    *(float4*)&Zo[off] = zn;
    int ci = off >> 10, n = off & 1023;
#pragma unroll
    for (int z = 0; z < 2; ++z) {
        float bz = BiasN[z * NOPEN + ci];
        ushort* Zz = Zct + z * (1032 * 128);
        Zz[(n + 4) * 128 + ci] = f2bf(zn.x + bz);
        Zz[(n + 5) * 128 + ci] = f2bf(zn.y + bz);
        Zz[(n + 6) * 128 + ci] = f2bf(zn.z + bz);
        Zz[(n + 7) * 128 + ci] = f2bf(zn.w + bz);
    }
}

// ---------------- closing: out = concat(Kclose @ Zc, Kclose @ Zold) ----------------
__global__ void k_close(const float* __restrict__ Kclose, const float* __restrict__ Zc,
                        const float* __restrict__ Zold, float* __restrict__ out) {
    int n = blockIdx.x * 256 + threadIdx.x;
    int o = blockIdx.y;
    const float* Zb = blockIdx.z ? Zold : Zc;
    float a = 0.f;
#pragma unroll
    for (int c = 0; c < NOPEN; ++c) a = fmaf(Kclose[o * NOPEN + c], Zb[c * NN + n], a);
    out[blockIdx.z * (NCLOSE * NN) + o * NN + n] = a;
}

extern "C" void kernel_launch(void* const* d_in, const int* in_sizes, int n_in,
                              void* d_out, int out_size, void* d_ws, size_t ws_size,
                              hipStream_t stream) {
    const float* Z      = (const float*)d_in[0];
    const float* Kopen  = (const float*)d_in[1];
    const float* Kclose = (const float*)d_in[2];
    const float* W      = (const float*)d_in[3];
    const float* Bias   = (const float*)d_in[4];
    float* out = (float*)d_out;
    float* ws  = (float*)d_ws;

    // workspace layout (float units); state arrays [ci][n]
    float* Zb0   = ws + 0;         // 131072
    float* Zb1   = ws + 131072;    // 131072
    float* D2    = ws + 262144;    // 1048576
    float* C0    = ws + 1310720;   // 262144
    float* Tacc  = ws + 1572864;   // 131072
    float* P1    = ws + 1703936;   // 8*256*1024 = 2097152
    float* P2    = ws + 3801088;   // 8*128*1024 = 1048576
    float* Dh    = ws + 4849664;   // 1024
    float* sig   = ws + 4850688;   // 1024
    ushort* Lb  = (ushort*)(ws + 4851712); // 1024*1024 us
    ushort* C1b = (ushort*)(ws + 5376000); // 256*1024 us
    ushort* T1b = (ushort*)(ws + 5507072); // 128*1024 us
    ushort* Zct = (ushort*)(ws + 5572608); // 2*1032*128 us
    ushort* At0 = (ushort*)(ws + 5704704); // 1032*256 us
    ushort* At1 = (ushort*)(ws + 5836800); // 1032*256 us
    ushort* Wt  = (ushort*)(ws + 5968896); // 2*9*256*128 us
    ushort* WtT = (ushort*)(ws + 6263808); // 2*9*128*256 us  (end 6558720 floats = 26.2 MB)

    k_open<<<dim3(657), 256, 0, stream>>>(Kopen, Z, Zb0, Zb1, Bias, Zct, At0, At1,
                                          W, Wt, WtT, sig);

    float* Zc = Zb0;
    float* Zold = Zb1;
    for (int i = 0; i < NLAYERS; ++i) {
        if (i % 10 == 0) {
            k_d2<<<dim3(16, 32), 256, 0, stream>>>(Zc, D2, sig);
            k_deg<<<dim3(NN), 256, 0, stream>>>(D2, sig, Dh);
            k_L<<<dim3(NN), 256, 0, stream>>>(D2, sig, Dh, Lb);
        }
        k_conv<<<dim3(16, 8, 2), 256, 0, stream>>>(Zct, Wt, C0, C1b);
        k_s2<<<dim3(512), 256, 0, stream>>>(C1b, Lb, P1, C0, At0);
        k_s3<<<dim3(384), 256, 0, stream>>>(At0, WtT, Tacc, P1, At1);
        k_s4<<<dim3(128), 256, 0, stream>>>(At1, WtT, T1b);
        int lnext = (i + 1 < NLAYERS) ? i + 1 : NLAYERS - 1;
        k_s5<<<dim3(273), 256, 0, stream>>>(T1b, Lb, P2, W, Wt, WtT, sig,
                                            lnext, (i + 1 < NLAYERS) ? 1 : 0);
        k_leap<<<dim3(128), 256, 0, stream>>>(P2, Tacc, Zc, Zold,
                                              Bias + (size_t)lnext * 2 * NOPEN, Zct);
        float* tmp = Zc; Zc = Zold; Zold = tmp;
    }

    k_close<<<dim3(4, NCLOSE, 2), 256, 0, stream>>>(Kclose, Zc, Zold, out);
}